// Round 4
// baseline (114.602 us; speedup 1.0000x reference)
//
#include <hip/hip_runtime.h>
#include <hip/hip_bf16.h>
#include <stdint.h>

// R2NPropositionalLayer: per (b,t) with i,j,k = idx arrays[t]:
//   emb = 1 - (1 - x_i*x_j) * x_k
//   bb  = ((c_i && c_j) || !c_k) ? 1.0f : 0.0f
// c_bool arrives as int32.
// Round 4 mapping: lane handles 4 consecutive t (t0 = 4*(lane&15)); 16 lanes
// cover one row, 4 rows per wave per iter, 4 iters -> 16 rows/wave, 64/block.
// Fast path (indices affine 3t,3t+1,3t+2): x/cb needs per lane are 48
// contiguous, 48B-aligned bytes -> 3x dwordx4 loads each; both stores are one
// dwordx4. Halves VMEM instruction count vs round 3 and aligns everything.

union F4  { float4 v;    float f[4]; };
union F12 { float4 v[3]; float f[12]; };
union I12 { int4   v[3]; int   f[12]; };

__global__ __launch_bounds__(256) void r2n_prop_kernel64(
    const float* __restrict__ x,
    const int* __restrict__ cb,
    const int* __restrict__ i_idx,
    const int* __restrict__ j_idx,
    const int* __restrict__ k_idx,
    float* __restrict__ emb,
    float* __restrict__ bb,
    int C, long long Brows)
{
    const int lane = threadIdx.x & 63;
    const int wave = threadIdx.x >> 6;
    const int sub  = lane & 15;   // lane-within-row
    const int rsel = lane >> 4;   // row-within-group-of-4
    const int t0   = sub * 4;

    // Per-lane check of the affine pattern for its 4 t values; wave-uniform vote.
    bool ok = (C >= 192);
    #pragma unroll
    for (int q = 0; q < 4; ++q) {
        int t = t0 + q;
        ok = ok && (i_idx[t] == 3 * t) && (j_idx[t] == 3 * t + 1)
                && (k_idx[t] == 3 * t + 2);
    }
    const bool fast = __all(ok);

    const long long waveRow = ((long long)blockIdx.x * 4 + wave) * 16;

    if (fast) {
        #pragma unroll
        for (int it = 0; it < 4; ++it) {
            const long long b = waveRow + it * 4 + rsel;
            if (b >= Brows) break;
            const float4* xp = reinterpret_cast<const float4*>(x  + b * (long long)C + 3 * t0);
            const int4*   cp = reinterpret_cast<const int4*>  (cb + b * (long long)C + 3 * t0);
            F12 X; I12 Cc;
            X.v[0]  = xp[0]; X.v[1]  = xp[1]; X.v[2]  = xp[2];
            Cc.v[0] = cp[0]; Cc.v[1] = cp[1]; Cc.v[2] = cp[2];

            F4 eo, bo;
            #pragma unroll
            for (int q = 0; q < 4; ++q) {
                float xi = X.f[3 * q], xj = X.f[3 * q + 1], xk = X.f[3 * q + 2];
                eo.f[q] = fmaf(-(1.0f - xi * xj), xk, 1.0f);
                bo.f[q] = (((Cc.f[3 * q] != 0) && (Cc.f[3 * q + 1] != 0))
                           || (Cc.f[3 * q + 2] == 0)) ? 1.0f : 0.0f;
            }
            *reinterpret_cast<float4*>(emb + b * 64 + t0) = eo.v;
            *reinterpret_cast<float4*>(bb  + b * 64 + t0) = bo.v;
        }
    } else {
        #pragma unroll
        for (int it = 0; it < 4; ++it) {
            const long long b = waveRow + it * 4 + rsel;
            if (b >= Brows) break;
            const float* xr = x  + b * (long long)C;
            const int*   cr = cb + b * (long long)C;
            #pragma unroll
            for (int q = 0; q < 4; ++q) {
                int t = t0 + q;
                int i = i_idx[t], j = j_idx[t], k = k_idx[t];
                float e = fmaf(-(1.0f - xr[i] * xr[j]), xr[k], 1.0f);
                float bbv = (((cr[i] != 0) && (cr[j] != 0)) || (cr[k] == 0)) ? 1.0f : 0.0f;
                emb[b * 64 + t] = e;
                bb[b * 64 + t]  = bbv;
            }
        }
    }
}

// Generic fallback for T != 64 (never taken in this problem's config).
__global__ __launch_bounds__(256) void r2n_prop_generic(
    const float* __restrict__ x, const int* __restrict__ cb,
    const int* __restrict__ i_idx, const int* __restrict__ j_idx,
    const int* __restrict__ k_idx,
    float* __restrict__ emb, float* __restrict__ bb,
    int C, int T, long long BT)
{
    long long gid = (long long)blockIdx.x * blockDim.x + threadIdx.x;
    if (gid >= BT) return;
    int t = (int)(gid % T);
    long long b = gid / T;
    int i = i_idx[t], j = j_idx[t], k = k_idx[t];
    const float* xr = x  + b * (long long)C;
    const int*   cr = cb + b * (long long)C;
    float e = fmaf(-(1.0f - xr[i] * xr[j]), xr[k], 1.0f);
    float bbv = (((cr[i] != 0) && (cr[j] != 0)) || (cr[k] == 0)) ? 1.0f : 0.0f;
    emb[gid] = e;
    bb[gid]  = bbv;
}

extern "C" void kernel_launch(void* const* d_in, const int* in_sizes, int n_in,
                              void* d_out, int out_size, void* d_ws, size_t ws_size,
                              hipStream_t stream)
{
    const float* x    = (const float*)d_in[0];
    const int*   cb   = (const int*)d_in[1];
    const int*   iidx = (const int*)d_in[2];
    const int*   jidx = (const int*)d_in[3];
    const int*   kidx = (const int*)d_in[4];

    float* emb = (float*)d_out;

    int T = in_sizes[2];                      // 64
    long long BT = (long long)out_size / 2;   // B*T
    long long B  = BT / T;
    int C = (int)((long long)in_sizes[0] / B); // 256

    float* bb = emb + BT;

    if (T == 64) {
        // 4 waves/block, 16 rows/wave -> 64 rows/block
        long long nblocks = (B + 63) / 64;
        r2n_prop_kernel64<<<(uint32_t)nblocks, 256, 0, stream>>>(
            x, cb, iidx, jidx, kidx, emb, bb, C, B);
    } else {
        long long nblocks = (BT + 255) / 256;
        r2n_prop_generic<<<(uint32_t)nblocks, 256, 0, stream>>>(
            x, cb, iidx, jidx, kidx, emb, bb, C, T, BT);
    }
}

// Round 5
// 87.555 us; speedup vs baseline: 1.3089x; 1.3089x over previous
//
#include <hip/hip_runtime.h>
#include <hip/hip_bf16.h>
#include <stdint.h>

// R2NPropositionalLayer: per (b,t) with i,j,k = idx arrays[t]:
//   emb = 1 - (1 - x_i*x_j) * x_k
//   bb  = ((c_i && c_j) || !c_k) ? 1.0f : 0.0f
// c_bool arrives as int32.
// Round 5: revert to round-3 mapping (lane = t -> wave reads 768B contiguous
// per row via dwordx3; round-4's strided dwordx4 split transactions and
// regressed). New: full-tile path issues all 8 loads (4 rows x {x,cb}) with
// no intervening control flow so the compiler batches them under one
// vmcnt wait (latency hiding via ILP), and outputs use nontemporal stores
// (streaming, never re-read -> skip L2 write-allocate).

#define ROWS_PER_WAVE 4

union F3 { float f[3]; };
union I3 { int   f[3]; };

__global__ __launch_bounds__(256) void r2n_prop_kernel(
    const float* __restrict__ x,
    const int* __restrict__ cb,       // bool pushed as int32
    const int* __restrict__ i_idx,
    const int* __restrict__ j_idx,
    const int* __restrict__ k_idx,
    float* __restrict__ emb,
    float* __restrict__ bb,
    int C, int T, long long Brows)
{
    const int lane = threadIdx.x & 63;
    const int wave = threadIdx.x >> 6;
    const long long rowBase = ((long long)blockIdx.x * 4 + wave) * ROWS_PER_WAVE;

    const int t = lane;
    if (t >= T) return;               // T==64 in practice

    const int i = i_idx[t];
    const int j = j_idx[t];
    const int k = k_idx[t];

    const bool fast = (j == i + 1) && (k == i + 2);

    if (fast && rowBase + ROWS_PER_WAVE <= Brows) {
        // ---- batched loads: 8 independent VMEM ops, one wait ----
        F3 X[ROWS_PER_WAVE];
        I3 Cc[ROWS_PER_WAVE];
        #pragma unroll
        for (int r = 0; r < ROWS_PER_WAVE; ++r) {
            const long long b = rowBase + r;
            __builtin_memcpy(&X[r],  x  + b * (long long)C + i, 12); // dwordx3
            __builtin_memcpy(&Cc[r], cb + b * (long long)C + i, 12);
        }
        #pragma unroll
        for (int r = 0; r < ROWS_PER_WAVE; ++r) {
            const long long b = rowBase + r;
            float e = fmaf(-(1.0f - X[r].f[0] * X[r].f[1]), X[r].f[2], 1.0f);
            float bbv = (((Cc[r].f[0] != 0) && (Cc[r].f[1] != 0))
                         || (Cc[r].f[2] == 0)) ? 1.0f : 0.0f;
            const long long o = b * (long long)T + t;
            __builtin_nontemporal_store(e,   emb + o);
            __builtin_nontemporal_store(bbv, bb  + o);
        }
    } else {
        for (int r = 0; r < ROWS_PER_WAVE; ++r) {
            const long long b = rowBase + r;
            if (b >= Brows) break;
            const float* xr = x  + b * (long long)C;
            const int*   cr = cb + b * (long long)C;
            float xi = xr[i], xj = xr[j], xk = xr[k];
            int   ci = cr[i], cj = cr[j], ck = cr[k];
            float e = fmaf(-(1.0f - xi * xj), xk, 1.0f);
            float bbv = (((ci != 0) && (cj != 0)) || (ck == 0)) ? 1.0f : 0.0f;
            const long long o = b * (long long)T + t;
            emb[o] = e;
            bb[o]  = bbv;
        }
    }
}

extern "C" void kernel_launch(void* const* d_in, const int* in_sizes, int n_in,
                              void* d_out, int out_size, void* d_ws, size_t ws_size,
                              hipStream_t stream)
{
    const float* x    = (const float*)d_in[0];
    const int*   cb   = (const int*)d_in[1];
    const int*   iidx = (const int*)d_in[2];
    const int*   jidx = (const int*)d_in[3];
    const int*   kidx = (const int*)d_in[4];

    float* emb = (float*)d_out;

    int T = in_sizes[2];                      // 64
    long long BT = (long long)out_size / 2;   // B*T
    long long B  = BT / T;
    int C = (int)((long long)in_sizes[0] / B); // 256

    float* bb = emb + BT;

    // 4 waves/block, ROWS_PER_WAVE rows per wave -> 16 rows/block
    long long rowsPerBlock = 4LL * ROWS_PER_WAVE;
    long long nblocks = (B + rowsPerBlock - 1) / rowsPerBlock;

    r2n_prop_kernel<<<(uint32_t)nblocks, 256, 0, stream>>>(
        x, cb, iidx, jidx, kidx, emb, bb, C, T, B);
}